// Round 6
// baseline (562.738 us; speedup 1.0000x reference)
//
#include <hip/hip_runtime.h>
#include <hip/hip_bf16.h>
#include <stdint.h>
#include <stddef.h>

// Problem dims
#define NB   16
#define CIN  256
#define HIN  128
#define WIN  128
#define COUT 512
#define HO   64
#define WO   64
#define HBL  129   // blurred spatial size

typedef __attribute__((ext_vector_type(8))) __bf16 bf16x8;
typedef __attribute__((ext_vector_type(4))) float  f32x4;

__device__ __forceinline__ void gld_lds16(const void* g, void* l) {
  __builtin_amdgcn_global_load_lds(
      (const __attribute__((address_space(1))) void*)g,
      (__attribute__((address_space(3))) void*)l, 16, 0, 0);
}

__device__ __forceinline__ unsigned pack_bf16(float lo, float hi) {
  __hip_bfloat16 l = __float2bfloat16(lo), h = __float2bfloat16(hi);
  unsigned short ul = *(unsigned short*)&l, uh = *(unsigned short*)&h;
  return (unsigned)ul | ((unsigned)uh << 16);
}

// ---------------------------------------------------------------------------
// Blur v2 (unchanged, passed R0-R5): xb NHWC bf16, XCD-swizzled grid.
// ---------------------------------------------------------------------------
__global__ __launch_bounds__(512) void blur_kernel(
    const float* __restrict__ x,
    const float* __restrict__ bk,
    __hip_bfloat16* __restrict__ xb)
{
  __shared__ __hip_bfloat16 lout[CIN * 130];  // 66560 B

  const int bid0 = blockIdx.x;
  const int bid  = (bid0 & 7) * 258 + (bid0 >> 3);  // XCD-contiguous chunks
  const int n    = bid / HBL;
  const int io   = bid % HBL;
  const int t    = threadIdx.x;
  const int wave = t >> 6;
  const int lane = t & 63;
  const int half = lane >> 5;   // channel within pair
  const int g    = lane & 31;   // 4-col group

  const float K11 = bk[5];
  float a[4], b[4];
  #pragma unroll
  for (int u = 0; u < 4; ++u) a[u] = bk[u * 4 + 1] / K11;
  #pragma unroll
  for (int v = 0; v < 4; ++v) b[v] = bk[4 + v];

  int rr[4];
  #pragma unroll
  for (int u = 0; u < 4; ++u) {
    int r = io - 2 + u;
    if (r < 0 || r >= HIN) { a[u] = 0.f; r = 0; }  // uniform: fold into tap
    rr[u] = r;
  }

  #pragma unroll 2
  for (int cb = wave * 2; cb < CIN; cb += 16) {
    const int c = cb + half;
    const float4* xr = (const float4*)(x + ((size_t)(n * CIN + c) * HIN) * WIN);
    float4 vm = {0.f, 0.f, 0.f, 0.f};
    #pragma unroll
    for (int u = 0; u < 4; ++u) {
      const float4 rv = xr[rr[u] * 32 + g];
      vm.x += a[u] * rv.x; vm.y += a[u] * rv.y;
      vm.z += a[u] * rv.z; vm.w += a[u] * rv.w;
    }
    float vmm2 = __shfl_up(vm.z, 1);    // vmid[4g-2]
    float vmm1 = __shfl_up(vm.w, 1);    // vmid[4g-1]
    float vmp4 = __shfl_down(vm.x, 1);  // vmid[4g+4]
    if (g == 0)  { vmm2 = 0.f; vmm1 = 0.f; }
    if (g == 31) { vmp4 = 0.f; }
    const float o0 = b[0]*vmm2 + b[1]*vmm1 + b[2]*vm.x + b[3]*vm.y;
    const float o1 = b[0]*vmm1 + b[1]*vm.x + b[2]*vm.y + b[3]*vm.z;
    const float o2 = b[0]*vm.x + b[1]*vm.y + b[2]*vm.z + b[3]*vm.w;
    const float o3 = b[0]*vm.y + b[1]*vm.z + b[2]*vm.w + b[3]*vmp4;
    unsigned* dst = (unsigned*)&lout[c * 130 + 4 * g];
    dst[0] = pack_bf16(o0, o1);
    dst[1] = pack_bf16(o2, o3);
    if (g == 31)
      lout[c * 130 + 128] = __float2bfloat16(b[0]*vm.z + b[1]*vm.w);
  }

  __syncthreads();

  const size_t obase = ((size_t)(n * HBL + io)) * HBL * CIN;
  for (int e = t; e < 65 * 64; e += 512) {
    const int jp = e >> 6;
    const int l  = e & 63;
    const unsigned r0 = *(const unsigned*)&lout[(4*l + 0) * 130 + 2*jp];
    const unsigned r1 = *(const unsigned*)&lout[(4*l + 1) * 130 + 2*jp];
    const unsigned r2 = *(const unsigned*)&lout[(4*l + 2) * 130 + 2*jp];
    const unsigned r3 = *(const unsigned*)&lout[(4*l + 3) * 130 + 2*jp];
    uint2 s0, s1;
    s0.x = (r0 & 0xffffu) | (r1 << 16);
    s0.y = (r2 & 0xffffu) | (r3 << 16);
    s1.x = (r0 >> 16) | (r1 & 0xffff0000u);
    s1.y = (r2 >> 16) | (r3 & 0xffff0000u);
    *(uint2*)&xb[obase + (size_t)(2*jp) * CIN + 4*l] = s0;
    if (jp < 64)
      *(uint2*)&xb[obase + (size_t)(2*jp + 1) * CIN + 4*l] = s1;
  }
}

// ---------------------------------------------------------------------------
// Weight prep (unchanged): wt[tap][o][c] = bf16(w[o][c][kh][kw])
// ---------------------------------------------------------------------------
__global__ __launch_bounds__(256) void wprep_kernel(
    const float* __restrict__ w,
    __hip_bfloat16* __restrict__ wt)
{
  const int idx = blockIdx.x * 256 + threadIdx.x;
  if (idx >= 9 * COUT * CIN) return;
  const int c   = idx & (CIN - 1);
  const int o   = (idx >> 8) & (COUT - 1);
  const int tap = idx >> 17;
  wt[idx] = __float2bfloat16(w[(o * CIN + c) * 9 + tap]);
}

// ---------------------------------------------------------------------------
// Implicit GEMM v5: m201-style 8-PHASE schedule. 256x256 tile, 8 waves =
// 2(o-half:128) x 4(px-quarter:64). K = 72 subtiles of K32 (u = 0..71),
// 2 K64-tiles per iteration (4 subtiles), 18 iterations, 2 LDS buffers of
// 64 KB: [A-h0|A-h1|B-h0|B-h1] x 16 KB; buf(u) = (u>>1)&1, half = u&1.
// Per phase: {4 aw ds_read (+4 bx on odd phases) for ONE C-quadrant;
// one 16-KB stage part (2 gld_lds); [vmcnt@p4/p8]; barrier; lgkm(0);
// setprio1; 16 MFMA; setprio0; barrier}. Stage parts (iter i):
// p1:W(4i+3) p2:X(4i+4) p3:W(4i+4) p4:X(4i+5) p5:W(4i+5) p6:X(4i+6)
// p7:W(4i+6) p8:X(4i+7) — each region's last read is >=1 barrier before
// its overwrite; vmcnt(6)@p4/p8 leaves 3 parts in flight and completes
// every part that a following read needs (last iter p4 drains to 0).
// Swizzle/staging constants identical to R5 (measured 0 conflicts).
// ---------------------------------------------------------------------------
#define VMW(N) asm volatile("s_waitcnt vmcnt(" #N ")" ::: "memory")

#define MFMA1(QH, I, J)                                                       \
  acc[(QH)*4+(I)][(J)] = __builtin_amdgcn_mfma_f32_16x16x32_bf16(             \
      a##I, bx##J, acc[(QH)*4+(I)][(J)], 0, 0, 0)

#define PHASE(QH, DU, READB, STG, VMSTMT)                                     \
  {                                                                           \
    const int u_ = u0 + (DU);                                                 \
    const char* sA = lds + ((u_ >> 1) & 1) * 65536 + (u_ & 1) * 16384;        \
    const char* sB = sA + 32768;                                              \
    bf16x8 a0 = *(const bf16x8*)(sA + abase + ((QH)*4 + 0) * 1024);           \
    bf16x8 a1 = *(const bf16x8*)(sA + abase + ((QH)*4 + 1) * 1024);           \
    bf16x8 a2 = *(const bf16x8*)(sA + abase + ((QH)*4 + 2) * 1024);           \
    bf16x8 a3 = *(const bf16x8*)(sA + abase + ((QH)*4 + 3) * 1024);           \
    if (READB) {                                                              \
      bx0 = *(const bf16x8*)(sB + bbase + 0 * 1024);                          \
      bx1 = *(const bf16x8*)(sB + bbase + 1 * 1024);                          \
      bx2 = *(const bf16x8*)(sB + bbase + 2 * 1024);                          \
      bx3 = *(const bf16x8*)(sB + bbase + 3 * 1024);                          \
    }                                                                         \
    STG;                                                                      \
    VMSTMT;                                                                   \
    __builtin_amdgcn_s_barrier();                                             \
    asm volatile("s_waitcnt lgkmcnt(0)" ::: "memory");                        \
    __builtin_amdgcn_sched_barrier(0);                                        \
    __builtin_amdgcn_s_setprio(1);                                            \
    MFMA1(QH,0,0); MFMA1(QH,0,1); MFMA1(QH,0,2); MFMA1(QH,0,3);               \
    MFMA1(QH,1,0); MFMA1(QH,1,1); MFMA1(QH,1,2); MFMA1(QH,1,3);               \
    MFMA1(QH,2,0); MFMA1(QH,2,1); MFMA1(QH,2,2); MFMA1(QH,2,3);               \
    MFMA1(QH,3,0); MFMA1(QH,3,1); MFMA1(QH,3,2); MFMA1(QH,3,3);               \
    __builtin_amdgcn_s_setprio(0);                                            \
    __builtin_amdgcn_sched_barrier(0);                                        \
    __builtin_amdgcn_s_barrier();                                             \
    __builtin_amdgcn_sched_barrier(0);                                        \
  }

__global__ __launch_bounds__(512, 2) void gemm_kernel(
    const __hip_bfloat16* __restrict__ xb,    // [16][129][129][256]
    const __hip_bfloat16* __restrict__ wt,    // [9][512][256]
    const float* __restrict__ bias,           // [512]
    float* __restrict__ y)                    // [16][512][64][64]
{
  __shared__ __align__(16) char lds[2 * 65536];   // 128 KiB, 2 K64 buffers

  const int t    = threadIdx.x;
  const int wave = t >> 6;
  const int lane = t & 63;
  const int bid0 = blockIdx.x;
  const int bid  = (bid0 & 7) * 64 + (bid0 >> 3);  // XCD swizzle (512 = 8*64)
  const int nb   = bid & 1;    // 2 N-blocks (adjacent -> same XCD L2)
  const int mb   = bid >> 1;   // 256 M-blocks
  const int o0   = nb * 256;
  const int p0   = mb * 256;   // 256 pixels: rows h0..h0+3 x w=0..63 of imgn
  const int imgn = p0 >> 12;
  const int h0   = (p0 >> 6) & 63;

  const int wo  = wave >> 2;   // o-half (128 rows)
  const int wp  = wave & 3;    // px-quarter (64 rows)
  const int q   = lane >> 4;
  const int m16 = lane & 15;

  // ---- staging constants (identical to R5): per part, 2 gld_lds covering a
  // 16-KB operand region; inverse swizzle folded into global source address.
  long xg[2], wg[2];
  int  ldsoff[2];
  #pragma unroll
  for (int s = 0; s < 2; ++s) {
    const int ia = wave * 2 + s;
    const int Lr = ia * 8 + (lane >> 3);
    const int g3 = (lane & 7) ^ (Lr & 7);
    const int r  = 2 * Lr + (g3 >> 2);
    const int cq = (g3 & 3) * 8;
    const int hh = h0 + (r >> 6);
    const int ww = r & 63;
    xg[s] = ((long)(imgn * HBL + 2 * hh) * HBL + 2 * ww) * CIN + cq;
    wg[s] = (long)(o0 + r) * CIN + cq;
    ldsoff[s] = ia * 1024;   // wave-uniform
  }

  // ---- fragment base offsets within a 16-KB half-region (of/pf-invariant)
  const int g3f   = (((m16 & 1) << 2) | q) ^ ((m16 >> 1) & 7);
  const int abase = ((wo * 128 + m16) >> 1) * 128 + g3f * 16;
  const int bbase = ((wp * 64  + m16) >> 1) * 128 + g3f * 16;

  f32x4 acc[8][4];
  #pragma unroll
  for (int of = 0; of < 8; ++of)
    #pragma unroll
    for (int pf = 0; pf < 4; ++pf)
      acc[of][pf] = (f32x4){0.f, 0.f, 0.f, 0.f};

  // subtile u: tap = u>>3, cb = (u&7)*32; region = buf(u)*64K + half(u)*16K
  auto stageW = [&](int u) {
    const long woff = (long)(u >> 3) * (COUT * CIN) + (u & 7) * 32;
    char* d = lds + ((u >> 1) & 1) * 65536 + (u & 1) * 16384;
    gld_lds16(wt + woff + wg[0], d + ldsoff[0]);
    gld_lds16(wt + woff + wg[1], d + ldsoff[1]);
  };
  auto stageX = [&](int u) {
    const int  tap = u >> 3;
    const long xoff = (long)((tap / 3) * HBL + (tap % 3)) * CIN + (u & 7) * 32;
    char* d = lds + ((u >> 1) & 1) * 65536 + 32768 + (u & 1) * 16384;
    gld_lds16(xb + xoff + xg[0], d + ldsoff[0]);
    gld_lds16(xb + xoff + xg[1], d + ldsoff[1]);
  };

  // prologue: parts X0,W0,X1,W1,X2,W2,X3 (W3 arrives at iter-0 p1).
  // vmcnt(6) completes X0..W1 -> subtiles 0,1 resident for phases 1-4.
  stageX(0); stageW(0); stageX(1); stageW(1); stageX(2); stageW(2); stageX(3);
  VMW(6);
  __builtin_amdgcn_s_barrier();
  __builtin_amdgcn_sched_barrier(0);

  bf16x8 bx0, bx1, bx2, bx3;

  for (int i = 0; i < 18; ++i) {
    const int u0 = 4 * i;
    PHASE(0, 0, 1, stageW(u0 + 3),                     (void)0)
    PHASE(1, 0, 0, if (u0 + 4 < 72) stageX(u0 + 4),    (void)0)
    PHASE(0, 1, 1, if (u0 + 4 < 72) stageW(u0 + 4),    (void)0)
    PHASE(1, 1, 0, if (u0 + 5 < 72) stageX(u0 + 5),
          if (i < 17) { VMW(6); } else { VMW(0); })
    PHASE(0, 2, 1, if (u0 + 5 < 72) stageW(u0 + 5),    (void)0)
    PHASE(1, 2, 0, if (u0 + 6 < 72) stageX(u0 + 6),    (void)0)
    PHASE(0, 3, 1, if (u0 + 6 < 72) stageW(u0 + 6),    (void)0)
    PHASE(1, 3, 0, if (u0 + 7 < 72) stageX(u0 + 7),    VMW(6))
  }

  // ---- epilogue: D col = px (lane&15), row = o (q*4 + rg); scale + bias
  const float scale = 1.0f / 48.0f;
  #pragma unroll
  for (int of = 0; of < 8; ++of) {
    const int o = o0 + wo * 128 + of * 16 + q * 4;
    #pragma unroll
    for (int pf = 0; pf < 4; ++pf) {
      const int p  = p0 + wp * 64 + pf * 16 + m16;
      const int n  = p >> 12;
      const int hh = (p >> 6) & 63;
      const int ww = p & 63;
      const size_t obase = ((size_t)(n * COUT + o) * HO + hh) * WO + ww;
      #pragma unroll
      for (int rg = 0; rg < 4; ++rg) {
        const float v = acc[of][pf][rg] * scale + bias[o + rg];
        y[obase + (size_t)rg * (HO * WO)] = v;
      }
    }
  }
}

// ---------------------------------------------------------------------------
extern "C" void kernel_launch(void* const* d_in, const int* in_sizes, int n_in,
                              void* d_out, int out_size, void* d_ws, size_t ws_size,
                              hipStream_t stream) {
  const float* x  = (const float*)d_in[0];
  const float* w  = (const float*)d_in[1];
  const float* bs = (const float*)d_in[2];
  const float* bk = (const float*)d_in[3];
  float* y = (float*)d_out;

  // workspace: xb (NHWC blurred bf16, 136.3 MB) + wt (2.4 MB)
  __hip_bfloat16* xb = (__hip_bfloat16*)d_ws;
  __hip_bfloat16* wt = (__hip_bfloat16*)((char*)d_ws +
                       (size_t)NB * HBL * HBL * CIN * sizeof(__hip_bfloat16));

  hipLaunchKernelGGL(blur_kernel, dim3(NB * HBL), dim3(512), 0, stream, x, bk, xb);
  hipLaunchKernelGGL(wprep_kernel, dim3((9 * COUT * CIN + 255) / 256), dim3(256), 0, stream, w, wt);
  hipLaunchKernelGGL(gemm_kernel, dim3(256 * 2), dim3(512), 0, stream,
                     xb, wt, bs, y);
}